// Round 5
// baseline (137.304 us; speedup 1.0000x reference)
//
#include <hip/hip_runtime.h>
#include <stdint.h>

#define COLUMNS   1024
#define CELLS     16
#define NUM_CELLS (COLUMNS * CELLS)   // 16384
#define SEGS      32
#define SYNS      128
#define ACT_THR   10
#define NB        2048                // blocks for the big scans
#define WPB       4                   // waves per block (256 threads)

typedef int            i32x4 __attribute__((ext_vector_type(4)));
typedef float          f32x4 __attribute__((ext_vector_type(4)));
typedef unsigned short u16x4 __attribute__((ext_vector_type(4)));

template<typename T>
__device__ __forceinline__ T ntload(const T* p) { return __builtin_nontemporal_load(p); }

// ---------------------------------------------------------------------------
// Plan kernel (1 block, 1024 thr): pack prev bits (dtype auto-detect),
// ordered compaction of active columns, learnflag.
// ---------------------------------------------------------------------------
__global__ __launch_bounds__(1024) void plan_kernel(
    const void* __restrict__ prev, const int* __restrict__ x,
    const float* __restrict__ mod, uint32_t* __restrict__ prevbits,
    int* __restrict__ acols, int* __restrict__ acount, int* __restrict__ learnflag)
{
    __shared__ int s_isu8, s_any;
    __shared__ int wcnt[16], woff[16];
    const int t = threadIdx.x;
    const int* pi = (const int*)prev;
    if (t == 0) { s_isu8 = 0; s_any = 0; }
    __syncthreads();
    // int32-bool: every word 0/1. uint8-bool (random 0/1 bytes): a word >1 whp.
    int bad = 0;
    for (int k = t; k < NUM_CELLS / 4; k += 1024)
        if ((unsigned)pi[k] > 1u) bad = 1;
    if (bad) atomicOr(&s_isu8, 1);
    __syncthreads();

    if (t < 512) {
        uint32_t m = 0;
        if (s_isu8) {
            const unsigned char* p = (const unsigned char*)prev + (size_t)t * 32;
            #pragma unroll
            for (int j = 0; j < 32; ++j) m |= (p[j] ? 1u : 0u) << j;
        } else {
            const int* p = pi + (size_t)t * 32;
            #pragma unroll
            for (int j = 0; j < 32; ++j) m |= (p[j] ? 1u : 0u) << j;
        }
        prevbits[t] = m;
        if (m) atomicOr(&s_any, 1);
    }

    // ordered active-column compaction (1024 threads = 16 waves)
    const int ca = (x[t] != 0) ? 1 : 0;
    unsigned long long b = __ballot(ca != 0);
    const int wid = t >> 6, ln = t & 63;
    if (ln == 0) wcnt[wid] = __popcll(b);
    __syncthreads();
    if (t == 0) {
        int s = 0;
        for (int i = 0; i < 16; ++i) { woff[i] = s; s += wcnt[i]; }
        *acount = s;
        *learnflag = ((mod[0] != 0.0f) && s_any) ? 1 : 0;
    }
    __syncthreads();
    if (ca) acols[woff[wid] + __popcll(b & ((1ULL << ln) - 1ULL))] = t;
}

// ---------------------------------------------------------------------------
// Phase 1+2 fused: persistent wave-per-cell. Reduction is BALLOT-based:
// per-segment counts come from s_bcnt1 on wave-uniform ballot masks (scalar
// pipe, no DS ops, no cross-lane latency). fire/bestkey are wave-uniform.
// ---------------------------------------------------------------------------
template<bool PACK>
__global__ __launch_bounds__(256) void phase1_kernel(
    const uint32_t* __restrict__ prevbits, const int* __restrict__ acols,
    const int* __restrict__ acount,
    const int* __restrict__ conn, const float* __restrict__ vol,
    const float* __restrict__ cons, unsigned short* __restrict__ packed,
    unsigned char* __restrict__ pred1, unsigned char* __restrict__ bestseg)
{
    __shared__ uint32_t sbits[NUM_CELLS / 32];
    for (int i = threadIdx.x; i < NUM_CELLS / 32; i += 256) sbits[i] = prevbits[i];
    __syncthreads();

    const int nc   = *acount * CELLS;
    const int wv   = threadIdx.x >> 6;
    const int ln   = threadIdx.x & 63;
    const int half = ln >> 5;
    const int l32  = ln & 31;
    const int gw   = blockIdx.x * WPB + wv;   // global wave id

    for (int idx = gw; idx < nc; idx += NB * WPB) {
        const int cell = acols[idx >> 4] * CELLS + (idx & 15);
        const size_t base = (size_t)cell * (SEGS * SYNS);
        int fire = 0, bestkey = 0;
        #pragma unroll 4
        for (int k = 0; k < 16; ++k) {
            const int segA = k * 2;               // lanes 0-31: segA, 32-63: segA+1
            const size_t off = base + (size_t)(segA + half) * SYNS + l32 * 4;
            i32x4 c = ntload((const i32x4*)(conn + off));
            f32x4 v = ntload((const f32x4*)(vol + off));
            f32x4 q = ntload((const f32x4*)(cons + off));
            int i0 = min(max(c.x, 0), NUM_CELLS - 1);
            int i1 = min(max(c.y, 0), NUM_CELLS - 1);
            int i2 = min(max(c.z, 0), NUM_CELLS - 1);
            int i3 = min(max(c.w, 0), NUM_CELLS - 1);
            int p0 = (sbits[i0 >> 5] >> (i0 & 31)) & 1;
            int p1 = (sbits[i1 >> 5] >> (i1 & 31)) & 1;
            int p2 = (sbits[i2 >> 5] >> (i2 & 31)) & 1;
            int p3 = (sbits[i3 >> 5] >> (i3 & 31)) & 1;
            int cn0 = ((v.x > 0.5f) || (q.x > 0.5f)) ? 1 : 0;
            int cn1 = ((v.y > 0.5f) || (q.y > 0.5f)) ? 1 : 0;
            int cn2 = ((v.z > 0.5f) || (q.z > 0.5f)) ? 1 : 0;
            int cn3 = ((v.w > 0.5f) || (q.w > 0.5f)) ? 1 : 0;
            if (PACK) {
                u16x4 pk;
                pk.x = (unsigned short)(i0 | (cn0 << 14));
                pk.y = (unsigned short)(i1 | (cn1 << 14));
                pk.z = (unsigned short)(i2 | (cn2 << 14));
                pk.w = (unsigned short)(i3 | (cn3 << 14));
                *(u16x4*)(packed + off) = pk;
            }
            unsigned long long bc0 = __ballot(cn0 && p0);
            unsigned long long bc1 = __ballot(cn1 && p1);
            unsigned long long bc2 = __ballot(cn2 && p2);
            unsigned long long bc3 = __ballot(cn3 && p3);
            unsigned long long bp0 = __ballot(p0 != 0);
            unsigned long long bp1 = __ballot(p1 != 0);
            unsigned long long bp2 = __ballot(p2 != 0);
            unsigned long long bp3 = __ballot(p3 != 0);
            int cA = __popcll(bc0 & 0xFFFFFFFFull) + __popcll(bc1 & 0xFFFFFFFFull)
                   + __popcll(bc2 & 0xFFFFFFFFull) + __popcll(bc3 & 0xFFFFFFFFull);
            int cB = __popcll(bc0 >> 32) + __popcll(bc1 >> 32)
                   + __popcll(bc2 >> 32) + __popcll(bc3 >> 32);
            int oA = __popcll(bp0 & 0xFFFFFFFFull) + __popcll(bp1 & 0xFFFFFFFFull)
                   + __popcll(bp2 & 0xFFFFFFFFull) + __popcll(bp3 & 0xFFFFFFFFull);
            int oB = __popcll(bp0 >> 32) + __popcll(bp1 >> 32)
                   + __popcll(bp2 >> 32) + __popcll(bp3 >> 32);
            fire |= (cA >= ACT_THR) | (cB >= ACT_THR);
            bestkey = max(bestkey, (oA << 8) | (255 - segA));   // first-max tiebreak
            bestkey = max(bestkey, (oB << 8) | (254 - segA));
        }
        if (ln == 0) {
            pred1[cell]   = (unsigned char)(fire ? 1 : 0);
            bestseg[cell] = (unsigned char)(255 - (bestkey & 0xFF));
        }
    }
}

// ---------------------------------------------------------------------------
// Mid (1 block, 1024 thr = 1 col/thread): col_has_pred, new_active floats +
// packed bits, acc; zero-fills new_predictive (phase3 overwrites active cells).
// ---------------------------------------------------------------------------
__global__ __launch_bounds__(1024) void mid_kernel(
    const int* __restrict__ x, const unsigned char* __restrict__ pred1,
    uint32_t* __restrict__ newbits, float* __restrict__ out)
{
    __shared__ unsigned char s_hp[COLUMNS];
    __shared__ unsigned char s_act[COLUMNS];
    __shared__ int s_nact, s_npred;
    const int t = threadIdx.x;
    if (t == 0) { s_nact = 0; s_npred = 0; }
    __syncthreads();

    {
        const int col = t;
        int ca = (x[col] != 0) ? 1 : 0;
        int hp = 0;
        if (ca) {
            #pragma unroll
            for (int k = 0; k < CELLS; ++k) hp |= pred1[col * CELLS + k];
            hp = hp ? 1 : 0;
        }
        s_act[col] = (unsigned char)ca;
        s_hp[col]  = (unsigned char)hp;
        unsigned long long ba = __ballot(ca != 0);
        unsigned long long bp = __ballot((ca && hp) != 0);
        if ((t & 63) == 0) {
            atomicAdd(&s_nact, __popcll(ba));
            atomicAdd(&s_npred, __popcll(bp));
        }
    }
    __syncthreads();

    if (t < NUM_CELLS / 32) {
        uint32_t m = 0;
        #pragma unroll
        for (int j = 0; j < 32; ++j) {
            const int cell = t * 32 + j;
            const int col  = cell >> 4;
            int na = s_act[col] && (s_hp[col] ? (pred1[cell] != 0) : 1);
            m |= (uint32_t)(na ? 1u : 0u) << j;
        }
        newbits[t] = m;
    }
    for (int i = t; i < NUM_CELLS; i += 1024) {
        const int col = i >> 4;
        int na = s_act[col] && (s_hp[col] ? (pred1[i] != 0) : 1);
        out[i] = na ? 1.0f : 0.0f;
        out[NUM_CELLS + i] = 0.0f;   // default new_predictive (inactive cols)
    }
    __syncthreads();

    if (t == 0) {
        float acc = (s_nact > 0) ? (float)s_npred / (float)max(s_nact, 1) : 1.0f;
        out[2 * NUM_CELLS] = acc;
    }
}

// ---------------------------------------------------------------------------
// Phase 3: persistent wave-per-cell, ballot reduction. PACKED path streams
// only the uint16 sideband; the single updated segment of a winner cell
// re-reads its vol/cons row (clip(x,0,1)>0.5 == x>0.5, exact).
// ---------------------------------------------------------------------------
template<bool PACKED>
__global__ __launch_bounds__(256) void phase3_kernel(
    const uint32_t* __restrict__ prevbits, const uint32_t* __restrict__ newbits,
    const int* __restrict__ acols, const int* __restrict__ acount,
    const int* __restrict__ learnflag, const float* __restrict__ mod,
    const unsigned short* __restrict__ packed, const int* __restrict__ conn,
    const float* __restrict__ vol, const float* __restrict__ cons,
    const unsigned char* __restrict__ bestseg, float* __restrict__ outpred)
{
    __shared__ uint32_t snew[NUM_CELLS / 32];
    __shared__ uint32_t sprev[NUM_CELLS / 32];
    for (int i = threadIdx.x; i < NUM_CELLS / 32; i += 256) {
        snew[i]  = newbits[i];
        sprev[i] = prevbits[i];
    }
    __syncthreads();

    const int nc   = *acount * CELLS;
    const int lf   = *learnflag;
    const float d  = mod[0] * 0.1f;
    const int wv   = threadIdx.x >> 6;
    const int ln   = threadIdx.x & 63;
    const int half = ln >> 5;
    const int l32  = ln & 31;
    const int gw   = blockIdx.x * WPB + wv;

    for (int idx = gw; idx < nc; idx += NB * WPB) {
        const int cell = acols[idx >> 4] * CELLS + (idx & 15);
        const size_t base = (size_t)cell * (SEGS * SYNS);
        const int na  = (snew[cell >> 5] >> (cell & 31)) & 1;
        const int upd = (lf && na) ? (int)bestseg[cell] : -1;
        int fire = 0;
        #pragma unroll 4
        for (int k = 0; k < 16; ++k) {
            const int segA = k * 2;
            const int seg  = segA + half;
            const size_t off = base + (size_t)seg * SYNS + l32 * 4;
            int i0, i1, i2, i3, cn0, cn1, cn2, cn3;
            if (PACKED) {
                u16x4 pk = *(const u16x4*)(packed + off);
                i0 = pk.x & 0x3FFF; cn0 = (pk.x >> 14) & 1;
                i1 = pk.y & 0x3FFF; cn1 = (pk.y >> 14) & 1;
                i2 = pk.z & 0x3FFF; cn2 = (pk.z >> 14) & 1;
                i3 = pk.w & 0x3FFF; cn3 = (pk.w >> 14) & 1;
                if (seg == upd) {
                    f32x4 v = *(const f32x4*)(vol + off);
                    f32x4 q = *(const f32x4*)(cons + off);
                    int pp0 = (sprev[i0 >> 5] >> (i0 & 31)) & 1;
                    int pp1 = (sprev[i1 >> 5] >> (i1 & 31)) & 1;
                    int pp2 = (sprev[i2 >> 5] >> (i2 & 31)) & 1;
                    int pp3 = (sprev[i3 >> 5] >> (i3 & 31)) & 1;
                    cn0 = ((v.x + (pp0 ? d : -d)) > 0.5f) || (q.x > 0.5f);
                    cn1 = ((v.y + (pp1 ? d : -d)) > 0.5f) || (q.y > 0.5f);
                    cn2 = ((v.z + (pp2 ? d : -d)) > 0.5f) || (q.z > 0.5f);
                    cn3 = ((v.w + (pp3 ? d : -d)) > 0.5f) || (q.w > 0.5f);
                }
            } else {
                i32x4 c = ntload((const i32x4*)(conn + off));
                f32x4 v = ntload((const f32x4*)(vol + off));
                f32x4 q = ntload((const f32x4*)(cons + off));
                i0 = min(max(c.x, 0), NUM_CELLS - 1);
                i1 = min(max(c.y, 0), NUM_CELLS - 1);
                i2 = min(max(c.z, 0), NUM_CELLS - 1);
                i3 = min(max(c.w, 0), NUM_CELLS - 1);
                float vx = v.x, vy = v.y, vz = v.z, vw = v.w;
                if (seg == upd) {
                    int pp0 = (sprev[i0 >> 5] >> (i0 & 31)) & 1;
                    int pp1 = (sprev[i1 >> 5] >> (i1 & 31)) & 1;
                    int pp2 = (sprev[i2 >> 5] >> (i2 & 31)) & 1;
                    int pp3 = (sprev[i3 >> 5] >> (i3 & 31)) & 1;
                    vx += pp0 ? d : -d; vy += pp1 ? d : -d;
                    vz += pp2 ? d : -d; vw += pp3 ? d : -d;
                }
                cn0 = (vx > 0.5f) || (q.x > 0.5f);
                cn1 = (vy > 0.5f) || (q.y > 0.5f);
                cn2 = (vz > 0.5f) || (q.z > 0.5f);
                cn3 = (vw > 0.5f) || (q.w > 0.5f);
            }
            int pn0 = (snew[i0 >> 5] >> (i0 & 31)) & 1;
            int pn1 = (snew[i1 >> 5] >> (i1 & 31)) & 1;
            int pn2 = (snew[i2 >> 5] >> (i2 & 31)) & 1;
            int pn3 = (snew[i3 >> 5] >> (i3 & 31)) & 1;
            unsigned long long b0 = __ballot(cn0 && pn0);
            unsigned long long b1 = __ballot(cn1 && pn1);
            unsigned long long b2 = __ballot(cn2 && pn2);
            unsigned long long b3 = __ballot(cn3 && pn3);
            int cA = __popcll(b0 & 0xFFFFFFFFull) + __popcll(b1 & 0xFFFFFFFFull)
                   + __popcll(b2 & 0xFFFFFFFFull) + __popcll(b3 & 0xFFFFFFFFull);
            int cB = __popcll(b0 >> 32) + __popcll(b1 >> 32)
                   + __popcll(b2 >> 32) + __popcll(b3 >> 32);
            fire |= (cA >= ACT_THR) | (cB >= ACT_THR);
        }
        if (ln == 0) outpred[cell] = fire ? 1.0f : 0.0f;
    }
}

// ---------------------------------------------------------------------------
extern "C" void kernel_launch(void* const* d_in, const int* in_sizes, int n_in,
                              void* d_out, int out_size, void* d_ws, size_t ws_size,
                              hipStream_t stream) {
    const int*   x    = (const int*)d_in[0];
    const float* mod  = (const float*)d_in[1];
    const void*  prev = d_in[2];                 // bool array (dtype auto-detected)
    const int*   conn = (const int*)d_in[3];
    const float* vol  = (const float*)d_in[4];
    const float* cons = (const float*)d_in[5];
    float* out = (float*)d_out;  // [0..N) new_active, [N..2N) new_predictive, [2N] acc

    char* ws = (char*)d_ws;
    uint32_t* prevbits  = (uint32_t*)(ws + 0);         // 2048 B
    uint32_t* newbits   = (uint32_t*)(ws + 2048);      // 2048 B
    int*      learnflag = (int*)(ws + 4096);
    int*      acount    = (int*)(ws + 4160);
    int*      acols     = (int*)(ws + 4352);           // 4 KiB
    unsigned char* pred1   = (unsigned char*)(ws + 8704);   // 16 KiB
    unsigned char* bestseg = (unsigned char*)(ws + 25088);  // 16 KiB
    unsigned short* packed = (unsigned short*)(ws + 65536); // 128 MiB
    const size_t packed_bytes = (size_t)NUM_CELLS * SEGS * SYNS * 2;
    const bool use_packed = ws_size >= (size_t)65536 + packed_bytes;

    plan_kernel<<<1, 1024, 0, stream>>>(prev, x, mod, prevbits, acols, acount,
                                        learnflag);
    if (use_packed)
        phase1_kernel<true><<<NB, 256, 0, stream>>>(prevbits, acols, acount, conn,
                                                    vol, cons, packed, pred1, bestseg);
    else
        phase1_kernel<false><<<NB, 256, 0, stream>>>(prevbits, acols, acount, conn,
                                                     vol, cons, packed, pred1, bestseg);
    mid_kernel<<<1, 1024, 0, stream>>>(x, pred1, newbits, out);
    if (use_packed)
        phase3_kernel<true><<<NB, 256, 0, stream>>>(prevbits, newbits, acols, acount,
                                                    learnflag, mod, packed, conn, vol,
                                                    cons, bestseg, out + NUM_CELLS);
    else
        phase3_kernel<false><<<NB, 256, 0, stream>>>(prevbits, newbits, acols, acount,
                                                     learnflag, mod, packed, conn, vol,
                                                     cons, bestseg, out + NUM_CELLS);
}